// Round 11
// baseline (333.042 us; speedup 1.0000x reference)
//
#include <hip/hip_runtime.h>
#include <hip/hip_bf16.h>

// MultiHeadSelfAttention: B=4, S=2048, D=1024, H=16, depth=64, eval mode.
// Inputs/outputs fp32 (per reference); internal compute bf16 MFMA + fp32 acc.
//
// Pipeline:
//   0) convert x fp32 -> xb bf16
//   1) transpose+convert weights -> WT bf16 (qkv concat, [3072][1024]), WoT
//   2) GEMM mode0: xb @ [Wq|Wk|Wv] + bias -> Q(*0.125*log2e,[B,H,S,64]),
//      K([B,H,S,64]), V^T([B,H,64,S] -> d_out[0,16M))
//   3) flash attention v13.1 -> O bf16 (d_out[16M,32M))
//   4) GEMM mode1: O @ Wo + bo + x(fp32 residual) -> Tmp BF16 [8192][1024]
//   5) layernorm(Tmp)*gamma+beta -> out fp32 (overwrites all of d_out)
//
// r10 NOTE: bench infra failed ("container failed twice") -- v13.1 never
// ran. This is an UNCHANGED resubmit of the r9->r10 kernel. No new code.
//
// Flash history (counters):
//   v10 (KV=64, O^T PV, transient staging) 128.8; v12 dbuf DMA pipeline
//   137.7 (pipeline correct, Pl cost 1 block/CU); v13 (r9): 32x32 MFMA, no
//   P LDS, dbuf DMA, 4 blocks/CU -> 112.7 us. MfmaUtil 27, VALU 61 (88%
//   combined -> stall gone; VALU is now the critical pipe).
//   SPILL RULE (4x): DATA regs live across a barrier -> scratch. DMA staging
//   (global_load_lds) uses no data regs -> immune.
//   v13.1: defer-rescale. At r4 (16x16, 45% VALU, 33% stall) it was
//   neutral -- regime mismatch. Now VALU-bound: skipping the 32-mul
//   O-rescale when __any(mx > m_old) is false is exact (al==1) and cuts
//   ~19% of per-kt VALU.
//   TRIPWIRES: absmax 0.03125 (exactness); WRITE_SIZE 16384 (spill).
//
// GEMM history:
//   v1 LDT=40 reg staging; v2 1-buf gload_lds regressed (exposed latency);
//   v3 XCD swizzle neutral-kept; v5 (r8) 2-phase DMA dbuf == v1, kept.
//   GEMM0+GEMM1 ~190 us combined (never in top-5: each < flash dur).
//   Once flash < GEMM0, counters will expose GEMM0 for a data-driven round.
//
// Workspace (56 MB total):
//   [0,        16777216)  xb  bf16 [8192][1024]   (dead after GEMM0)
//   [16777216, 23068672)  WT  bf16 [3072][1024]   (dead after GEMM0)
//   [23068672, 39845888)  Q   bf16                (dead after flash)
//   [39845888, 56623104)  K   bf16                (dead after flash)
//   [56623104, 58720256)  WoT bf16 [1024][1024]   (needed by GEMM1 -> placed last)
//   Tmp bf16 [0, 16777216) aliases dead xb when GEMM1 runs

typedef __bf16 bf16;
typedef __bf16 bf16x2 __attribute__((ext_vector_type(2)));
typedef __bf16 bf16x4 __attribute__((ext_vector_type(4)));
typedef __bf16 bf16x8 __attribute__((ext_vector_type(8)));
typedef float floatx4 __attribute__((ext_vector_type(4)));
typedef float floatx16 __attribute__((ext_vector_type(16)));

#define MFMA16(a, b, c) __builtin_amdgcn_mfma_f32_16x16x32_bf16((a), (b), (c), 0, 0, 0)
#define MFMA32(a, b, c) __builtin_amdgcn_mfma_f32_32x32x16_bf16((a), (b), (c), 0, 0, 0)

// async global->LDS DMA, 16 B per lane: lane i's data lands at lds_base+i*16
// (wave-uniform LDS base, PER-LANE global address). No VGPRs hold the data.
// Counts in vmcnt; __syncthreads' vmcnt(0) drain is the completion wait.
static __device__ __forceinline__ void gload16(const bf16* g, bf16* lds_base) {
    __builtin_amdgcn_global_load_lds(
        (__attribute__((address_space(1))) void*)(g),
        (__attribute__((address_space(3))) void*)(lds_base), 16, 0, 0);
}

// ---------------------------------------------------------------------------
// 0) fp32 -> bf16 convert (4 elems/thread)
__global__ __launch_bounds__(256) void convert_kernel(
    const float* __restrict__ x, bf16* __restrict__ xb)
{
    const int i = blockIdx.x * 256 + threadIdx.x;
    const float4 v = ((const float4*)x)[i];
    bf16x4 r;
    r[0] = (bf16)v.x; r[1] = (bf16)v.y; r[2] = (bf16)v.z; r[3] = (bf16)v.w;
    ((bf16x4*)xb)[i] = r;
}

// ---------------------------------------------------------------------------
// 1) 32x32 tiled transpose+convert: dst[n][k] = (bf16)src[k][n]; z picks W.
__global__ __launch_bounds__(256) void transpose_kernel(
    const float* __restrict__ Wq, const float* __restrict__ Wk,
    const float* __restrict__ Wv, const float* __restrict__ Wo,
    bf16* __restrict__ WT, bf16* __restrict__ WoT)
{
    __shared__ float tile[32][33];
    const int z = blockIdx.z;
    const float* src = (z == 0) ? Wq : (z == 1) ? Wk : (z == 2) ? Wv : Wo;
    bf16* dst = (z < 3) ? (WT + (long)z * 1024 * 1024) : WoT;
    const int n0 = blockIdx.x * 32, k0 = blockIdx.y * 32;
    const int tx = threadIdx.x & 31, ty = threadIdx.x >> 5;  // 8 rows x 32 cols
#pragma unroll
    for (int i = 0; i < 32; i += 8)
        tile[ty + i][tx] = src[(long)(k0 + ty + i) * 1024 + n0 + tx];
    __syncthreads();
#pragma unroll
    for (int i = 0; i < 32; i += 8)
        dst[(long)(n0 + ty + i) * 1024 + k0 + tx] = (bf16)tile[tx][ty + i];
}

// ---------------------------------------------------------------------------
// 2/4) GEMM C[M x N] = A[M x K] * Bt[N x K]^T, 128x128x32 tiles, 4 waves.
// v5 (r8-proven): T3 2-phase DMA pipeline: LDS double-buffer, ONE barrier
// per k-step; the barrier's vmcnt(0) drain completes the DMA issued LAST
// iteration (which had the whole 64-MFMA compute to fly under). LDT=32
// linear (b128 frag reads at the 8-lanes/16B-slot floor).
// Bijective XCD swizzle (nwg%8==0 both modes) kept.
// MODE 0: N=3072, epilogue scatters to Q (*0.125*log2e folded), K, Vt w/ bias.
// MODE 1: N=1024, epilogue Tmp = bf16(C + bias + X residual).
template <int MODE>
__global__ __launch_bounds__(256, 2) void gemm_kernel(
    const bf16* __restrict__ A, const bf16* __restrict__ Bt,
    const float* __restrict__ b0, const float* __restrict__ b1,
    const float* __restrict__ b2, const float* __restrict__ X,
    bf16* __restrict__ Qo, bf16* __restrict__ Ko, bf16* __restrict__ Vto,
    bf16* __restrict__ Tmpb, int N, int K)
{
    constexpr int LDT = 32;
    constexpr int NBX = (MODE == 0) ? 24 : 8;   // grid x-dim
    constexpr int NWG = NBX * 64;               // 1536 / 512, both % 8 == 0
    constexpr int CPX = NWG / 8;                // blocks per XCD chunk
    __shared__ __align__(16) bf16 As[2][128 * LDT];  // 2 x 8192 B
    __shared__ __align__(16) bf16 Bs[2][128 * LDT];  // 2 x 8192 B
    const int t = threadIdx.x;
    const int lane = t & 63;
    const int w = t >> 6;
    const int wm = w >> 1, wn = w & 1;  // 2x2 waves -> 64x64 each
    const int g = lane >> 4, c = lane & 15;

    // XCD-aware remap: HW id % 8 == XCD; give each XCD a contiguous chunk.
    const int id = blockIdx.y * NBX + blockIdx.x;
    const int swz = (id & 7) * CPX + (id >> 3);
    const int bm = (swz / NBX) * 128;
    const int bn = (swz % NBX) * 128;

    // DMA staging geometry (k-invariant): 512 chunks per matrix, 2 issues.
    const bf16* asrc[2];
    const bf16* bsrc[2];
    int ldsoff[2];
#pragma unroll
    for (int i = 0; i < 2; ++i) {
        const int ch = (i * 4 + w) * 64 + lane;   // 0..511
        const int row = ch >> 2, col = ch & 3;
        asrc[i] = A + (long)(bm + row) * K + col * 8;
        bsrc[i] = Bt + (long)(bn + row) * K + col * 8;
        ldsoff[i] = (i * 4 + w) * 512;            // elems
    }

    floatx4 acc[4][4];
#pragma unroll
    for (int i = 0; i < 4; ++i)
#pragma unroll
        for (int j = 0; j < 4; ++j) acc[i][j] = floatx4{0.f, 0.f, 0.f, 0.f};

    // prologue: stage slab 0 into buf 0 (drained by first loop-top barrier)
#pragma unroll
    for (int i = 0; i < 2; ++i) {
        gload16(asrc[i], &As[0][ldsoff[i]]);
        gload16(bsrc[i], &Bs[0][ldsoff[i]]);
    }

    int cur = 0;
    for (int k0 = 0; k0 < K; k0 += 32) {
        // vmcnt(0)+lgkmcnt(0) drain at barrier: buf[cur] staged for all
        // waves AND all waves done reading buf[cur^1] -> free to restage.
        __syncthreads();
        if (k0 + 32 < K) {  // issue next slab's DMA; flies under MFMAs below
#pragma unroll
            for (int i = 0; i < 2; ++i) {
                gload16(asrc[i] + k0 + 32, &As[cur ^ 1][ldsoff[i]]);
                gload16(bsrc[i] + k0 + 32, &Bs[cur ^ 1][ldsoff[i]]);
            }
        }
        bf16x8 af[4], bfv[4];
#pragma unroll
        for (int i = 0; i < 4; ++i)
            af[i] = *(const bf16x8*)&As[cur][(wm * 64 + i * 16 + c) * LDT + g * 8];
#pragma unroll
        for (int j = 0; j < 4; ++j)
            bfv[j] = *(const bf16x8*)&Bs[cur][(wn * 64 + j * 16 + c) * LDT + g * 8];
#pragma unroll
        for (int i = 0; i < 4; ++i)
#pragma unroll
            for (int j = 0; j < 4; ++j)
                acc[i][j] = MFMA16(af[i], bfv[j], acc[i][j]);
        cur ^= 1;
    }

    // Epilogue. C/D layout: col = c (lane&15), row = g*4 + reg.
    if (MODE == 0) {
#pragma unroll
        for (int j = 0; j < 4; ++j) {
            const int col = bn + wn * 64 + j * 16 + c;  // 0..3071
            const int sec = col >> 10;                  // 0=Q 1=K 2=V (uniform per j)
            const int nn = col & 1023;
            const int h = nn >> 6, dd = nn & 63;
            const float* bp = (sec == 0) ? b0 : (sec == 1) ? b1 : b2;
            const float bias = bp[nn];
#pragma unroll
            for (int i = 0; i < 4; ++i) {
                const int r0 = bm + wm * 64 + i * 16 + g * 4;
                if (sec == 2) {
                    bf16x4 pack;
#pragma unroll
                    for (int reg = 0; reg < 4; ++reg)
                        pack[reg] = (bf16)(acc[i][j][reg] + bias);
                    const int b_ = r0 >> 11, sr = r0 & 2047;  // r0 % 4 == 0, no 2048-cross
                    *(bf16x4*)&Vto[((long)(b_ * 16 + h) * 64 + dd) * 2048 + sr] = pack;
                } else {
#pragma unroll
                    for (int reg = 0; reg < 4; ++reg) {
                        const int r = r0 + reg;
                        const int b_ = r >> 11, sr = r & 2047;
                        const float v = acc[i][j][reg] + bias;
                        if (sec == 0)  // fold (1/8)*log2(e): softmax runs in exp2 domain
                            Qo[((long)(b_ * 16 + h) * 2048 + sr) * 64 + dd] =
                                (bf16)(v * 0.18033688011112042f);
                        else
                            Ko[((long)(b_ * 16 + h) * 2048 + sr) * 64 + dd] = (bf16)v;
                    }
                }
            }
        }
    } else {
#pragma unroll
        for (int j = 0; j < 4; ++j) {
            const int col = bn + wn * 64 + j * 16 + c;
            const float bias = b0[col];
#pragma unroll
            for (int i = 0; i < 4; ++i) {
#pragma unroll
                for (int reg = 0; reg < 4; ++reg) {
                    const int r = bm + wm * 64 + i * 16 + g * 4 + reg;
                    Tmpb[(long)r * N + col] =
                        (bf16)(acc[i][j][reg] + bias + X[(long)r * N + col]);
                }
            }
        }
    }
}

// ---------------------------------------------------------------------------
// 3) Flash attention v13.1: 32x32 MFMA + v12 DMA-dbuf pipeline, no P LDS,
// + defer-rescale (exact: skip 32-mul O-rescale when no column's max grew,
// al==1.0 then; wave-uniform __any branch; VALU is the critical pipe now).
// LDS = KVs dbuf only = 32768 B -> 4 blocks/CU. One barrier per kt (its
// vmcnt(0) drain = tile ready + other dbuf free); kt+1's DMA flies under
// kt's compute. Swizzle (proven r7): LDS[row][colL] = global[row][colL ^
// (row&7)] in 16B chunks; reads XOR chunk idx with (row&7).
// Per wave: 32 q rows (q = q0w + lane&31). QK: S^T[kv][q], A=K-frag,
// B=Q-frag, 2 kv-tiles x 4 depth-slabs = 8 MFMA32. C layout: col=lane&31=q,
// row kv = (reg&3)+8*(reg>>2)+4*hw (hw=lane>>5). Softmax: all 32 kv of a
// q-row live in lanes {l, l^32} -> 1 shfl_xor(32) reduce; single m/l.
// P: pack reg pairs to bf16x2 dwords dpk[tile][u] (kv = 2(u&1)+8(u>>1)+4hw);
// PV B-frag pb[slab] (kv run slab*16+hw*8..+7) = 2 own dwords + 2 from
// partner lane via shfl_xor(32) with hw-selected source expr (verified all
// 4 (hw,slab) cases, r9 absmax clean). PV: O^T[d][q], A=V^T-frag, B=pb,
// 2 d-tiles x 4 slabs = 8 MFMA32. Epilogue: q=lane&31 matches l domain ->
// direct 1/l, bf16x4 stores (d = dt*32+rg*8+hw*4+r).
// Grid (64 bh, 16 qt): head-major pins each head's blocks to one XCD.
__global__ __launch_bounds__(256, 2) void flash_kernel(
    const bf16* __restrict__ Q, const bf16* __restrict__ Kc,
    const bf16* __restrict__ Vt, bf16* __restrict__ O)
{
    __shared__ __align__(16) bf16 KVs[2][2][64 * 64]; // [dbuf][0=K,1=V] 32768 B
    const int t = threadIdx.x;
    const int lane = t & 63;
    const int w = t >> 6;
    const int l31 = lane & 31, hw = lane >> 5;
    const int bh = blockIdx.x;           // head-major: XCD-local K/V
    const int b_ = bh >> 4, h = bh & 15;
    const bf16* Qp = Q + (long)bh * 2048 * 64;
    const bf16* Kp = Kc + (long)bh * 2048 * 64;
    const bf16* Vp = Vt + (long)bh * 64 * 2048;
    const int q0w = blockIdx.y * 128 + w * 32;

    // DMA staging geometry (kt-invariant; kt adds 4096 elems for K, 64 for V)
    const bf16* ksrc[2];
    const bf16* vsrc[2];
    int ldsoff[2];
#pragma unroll
    for (int i = 0; i < 2; ++i) {
        const int ch = (i * 4 + w) * 64 + lane;  // linear LDS chunk 0..511
        const int row = ch >> 3, col = ch & 7;
        const int sw = col ^ (row & 7);          // inverse-swizzled source col
        ksrc[i] = Kp + (long)(row * 8 + sw) * 8;      // K: [kv=row][d-chunk sw]
        vsrc[i] = Vp + (long)row * 2048 + sw * 8;     // V^T: [d=row][kv-chunk sw]
        ldsoff[i] = (i * 4 + w) * 512;                // elems (chunk*8)
    }

    // Q fragments (B operand: n=q=l31, k-run = slab*16 + hw*8), whole-loop
    bf16x8 qf[4];
#pragma unroll
    for (int sl = 0; sl < 4; ++sl)
        qf[sl] = *(const bf16x8*)(Qp + (long)(q0w + l31) * 64 + sl * 16 + hw * 8);

    float m_c = -1e30f;  // per-lane: q = l31 (hw-uniform via shfl merge)
    float l_c = 0.f;
    floatx16 o32[2];     // O^T[d = dt*32 + (reg&3)+8(reg>>2)+4hw][q = l31]
#pragma unroll
    for (int dt = 0; dt < 2; ++dt)
#pragma unroll
        for (int i = 0; i < 16; ++i) o32[dt][i] = 0.f;

    // prologue: stage tile 0 into dbuf 0 (drained by loop-top barrier)
#pragma unroll
    for (int i = 0; i < 2; ++i) {
        gload16(ksrc[i], &KVs[0][0][ldsoff[i]]);
        gload16(vsrc[i], &KVs[0][1][ldsoff[i]]);
    }

    for (int kt = 0; kt < 32; ++kt) {
        // vmcnt(0)+lgkmcnt(0) drain at barrier: tile kt staged for all
        // waves AND all waves done with dbuf[cur^1] -> free to restage.
        __syncthreads();
        const int cur = kt & 1;
        if (kt + 1 < 32) {  // issue kt+1's DMA; flies under compute below
#pragma unroll
            for (int i = 0; i < 2; ++i) {
                gload16(ksrc[i] + (long)(kt + 1) * 4096, &KVs[cur ^ 1][0][ldsoff[i]]);
                gload16(vsrc[i] + (long)(kt + 1) * 64,   &KVs[cur ^ 1][1][ldsoff[i]]);
            }
        }
        const bf16* KsB = KVs[cur][0];
        const bf16* VsB = KVs[cur][1];

        // QK: S^T[kv][q] over 2 kv-tiles, 4 depth slabs (swizzled K reads)
        floatx16 s32[2];
#pragma unroll
        for (int kt_ = 0; kt_ < 2; ++kt_)
#pragma unroll
            for (int i = 0; i < 16; ++i) s32[kt_][i] = 0.f;
#pragma unroll
        for (int sl = 0; sl < 4; ++sl) {
            const int x = sl * 2 + hw;          // depth 16B-chunk
            const int r0 = l31, r1 = 32 + l31;  // r0&7 == r1&7
            const int xs = x ^ (r0 & 7);
            bf16x8 kf0 = *(const bf16x8*)&KsB[r0 * 64 + (xs << 3)];
            bf16x8 kf1 = *(const bf16x8*)&KsB[r1 * 64 + (xs << 3)];
            s32[0] = MFMA32(kf0, qf[sl], s32[0]);
            s32[1] = MFMA32(kf1, qf[sl], s32[1]);
        }

        // online softmax: all 32 kv of q-row in {lane, lane^32}
        float mx;
        {
            float tm[16];
#pragma unroll
            for (int i = 0; i < 16; ++i) tm[i] = fmaxf(s32[0][i], s32[1][i]);
            float a0 = fmaxf(fmaxf(tm[0], tm[1]), fmaxf(tm[2], tm[3]));
            float a1 = fmaxf(fmaxf(tm[4], tm[5]), fmaxf(tm[6], tm[7]));
            float a2 = fmaxf(fmaxf(tm[8], tm[9]), fmaxf(tm[10], tm[11]));
            float a3 = fmaxf(fmaxf(tm[12], tm[13]), fmaxf(tm[14], tm[15]));
            mx = fmaxf(fmaxf(a0, a1), fmaxf(a2, a3));
        }
        mx = fmaxf(mx, __shfl_xor(mx, 32, 64));
        const float m_old = m_c;
        const float mn = fmaxf(m_old, mx);
        const float al = __builtin_amdgcn_exp2f(m_old - mn);  // ==1.0 if no growth
        m_c = mn;
        float r0s = 0.f, r1s = 0.f, r2s = 0.f, r3s = 0.f;
#pragma unroll
        for (int kt_ = 0; kt_ < 2; ++kt_) {
#pragma unroll
            for (int i = 0; i < 16; i += 4) {
                s32[kt_][i + 0] = __builtin_amdgcn_exp2f(s32[kt_][i + 0] - mn);
                s32[kt_][i + 1] = __builtin_amdgcn_exp2f(s32[kt_][i + 1] - mn);
                s32[kt_][i + 2] = __builtin_amdgcn_exp2f(s32[kt_][i + 2] - mn);
                s32[kt_][i + 3] = __builtin_amdgcn_exp2f(s32[kt_][i + 3] - mn);
                r0s += s32[kt_][i + 0]; r1s += s32[kt_][i + 1];
                r2s += s32[kt_][i + 2]; r3s += s32[kt_][i + 3];
            }
        }
        float rs = (r0s + r1s) + (r2s + r3s);
        rs += __shfl_xor(rs, 32, 64);
        l_c = l_c * al + rs;  // al==1 exact when rescale skipped below
        // defer-rescale: only pay the 32 muls when some column's max grew.
        // Exact: al == exp2(0) == 1.0 otherwise. VALU is the critical pipe
        // (61% busy, 88% combined) so this saving is no longer stall-masked.
        if (__any(mx > m_old)) {
#pragma unroll
            for (int dt = 0; dt < 2; ++dt)
#pragma unroll
                for (int i = 0; i < 16; ++i) o32[dt][i] *= al;
        }

        // pack P to bf16 dwords: dpk[tile][u] = kv pair 2(u&1)+8(u>>1)+4hw
        uint32_t dpk[2][8];
#pragma unroll
        for (int kt_ = 0; kt_ < 2; ++kt_)
#pragma unroll
            for (int u = 0; u < 8; ++u) {
                bf16x2 p2;
                p2[0] = (bf16)s32[kt_][2 * u];
                p2[1] = (bf16)s32[kt_][2 * u + 1];
                dpk[kt_][u] = __builtin_bit_cast(uint32_t, p2);
            }

        // PV B-frags pb[slab]: kv run slab*16 + hw*8 .. +7. Own 2 dwords +
        // 2 from partner (lane^32); source expr hw-selected so the partner
        // provides what THIS half needs (verified all 4 (hw,slab) cases).
        bf16x8 pb[4];
#pragma unroll
        for (int sl = 0; sl < 4; ++sl) {
            const int kt_ = sl >> 1;
            const int ub = (sl & 1) * 4;
            const uint32_t eA = hw ? dpk[kt_][ub + 0] : dpk[kt_][ub + 2];
            const uint32_t eB = hw ? dpk[kt_][ub + 1] : dpk[kt_][ub + 3];
            const uint32_t rA = (uint32_t)__shfl_xor((int)eA, 32, 64);
            const uint32_t rB = (uint32_t)__shfl_xor((int)eB, 32, 64);
            uint4 fr;
            if (hw == 0)
                fr = make_uint4(dpk[kt_][ub + 0], dpk[kt_][ub + 1], rA, rB);
            else
                fr = make_uint4(rA, rB, dpk[kt_][ub + 2], dpk[kt_][ub + 3]);
            pb[sl] = __builtin_bit_cast(bf16x8, fr);
        }

        // PV: O^T[d][q] += V^T-frag x pb, 2 d-tiles x 4 kv-slabs (swizzled V)
#pragma unroll
        for (int sl = 0; sl < 4; ++sl) {
            const int x = sl * 2 + hw;  // kv 16B-chunk
#pragma unroll
            for (int dt = 0; dt < 2; ++dt) {
                const int row = dt * 32 + l31;
                bf16x8 vf = *(const bf16x8*)&VsB[row * 64 + ((x ^ (row & 7)) << 3)];
                o32[dt] = MFMA32(vf, pb[sl], o32[dt]);
            }
        }
    }

    // epilogue: q = l31 matches l domain -> direct 1/l, bf16x4 stores
    const float linv = 1.0f / l_c;
    const int q = q0w + l31;
#pragma unroll
    for (int dt = 0; dt < 2; ++dt)
#pragma unroll
        for (int rg = 0; rg < 4; ++rg) {
            bf16x4 pk;
#pragma unroll
            for (int r = 0; r < 4; ++r) pk[r] = (bf16)(o32[dt][rg * 4 + r] * linv);
            const int d0 = dt * 32 + rg * 8 + hw * 4;
            *(bf16x4*)&O[((long)b_ * 2048 + q) * 1024 + h * 64 + d0] = pk;
        }
}

// ---------------------------------------------------------------------------
// 5) LayerNorm over rows of Tmp (bf16), one block per row, fp32 out.
__global__ __launch_bounds__(256, 2) void ln_kernel(
    const bf16* __restrict__ Tmp, const float* __restrict__ gamma,
    const float* __restrict__ beta, float* __restrict__ out)
{
    const int row = blockIdx.x;
    const int t = threadIdx.x;
    const int lane = t & 63, w = t >> 6;
    const bf16x4 vb = ((const bf16x4*)(Tmp + (long)row * 1024))[t];
    const float xv[4] = {(float)vb[0], (float)vb[1], (float)vb[2], (float)vb[3]};
    float s = xv[0] + xv[1] + xv[2] + xv[3];
    float ss = xv[0] * xv[0] + xv[1] * xv[1] + xv[2] * xv[2] + xv[3] * xv[3];
#pragma unroll
    for (int off = 1; off < 64; off <<= 1) {
        s += __shfl_xor(s, off, 64);
        ss += __shfl_xor(ss, off, 64);
    }
    __shared__ float sb[4], ssb[4];
    if (lane == 0) { sb[w] = s; ssb[w] = ss; }
    __syncthreads();
    s = sb[0] + sb[1] + sb[2] + sb[3];
    ss = ssb[0] + ssb[1] + ssb[2] + ssb[3];
    const float mu = s * (1.0f / 1024.0f);
    const float var = ss * (1.0f / 1024.0f) - mu * mu;
    const float inv = rsqrtf(var + 1e-6f);
    const float4 gm = ((const float4*)gamma)[t];
    const float4 bt = ((const float4*)beta)[t];
    float4 r;
    r.x = (xv[0] - mu) * inv * gm.x + bt.x;
    r.y = (xv[1] - mu) * inv * gm.y + bt.y;
    r.z = (xv[2] - mu) * inv * gm.z + bt.z;
    r.w = (xv[3] - mu) * inv * gm.w + bt.w;
    ((float4*)(out + (long)row * 1024))[t] = r;
}

// ---------------------------------------------------------------------------
extern "C" void kernel_launch(void* const* d_in, const int* in_sizes, int n_in,
                              void* d_out, int out_size, void* d_ws, size_t ws_size,
                              hipStream_t stream)
{
    const float* x     = (const float*)d_in[0];
    const float* Wq    = (const float*)d_in[1];
    const float* bq    = (const float*)d_in[2];
    const float* Wk    = (const float*)d_in[3];
    const float* bk    = (const float*)d_in[4];
    const float* Wv    = (const float*)d_in[5];
    const float* bv    = (const float*)d_in[6];
    const float* Wo    = (const float*)d_in[7];
    const float* bo    = (const float*)d_in[8];
    const float* gamma = (const float*)d_in[9];
    const float* beta  = (const float*)d_in[10];
    float* out = (float*)d_out;

    char* ws = (char*)d_ws;
    bf16* xb   = (bf16*)(ws);                   // [0, 16777216)
    bf16* WT   = (bf16*)(ws + 16777216);        // [16777216, 23068672)
    bf16* Qb   = (bf16*)(ws + 23068672);        // [23068672, 39845888)
    bf16* Kb   = (bf16*)(ws + 39845888);        // [39845888, 56623104)
    bf16* WoT  = (bf16*)(ws + 56623104);        // [56623104, 58720256)
    bf16* Tmpb = (bf16*)(ws);                   // [0, 16777216) alias dead xb
    bf16* Vtb  = (bf16*)d_out;                  // V^T parks in d_out[0, 16M)
    bf16* Ob   = (bf16*)((char*)d_out + 16777216);  // O parks in d_out[16M, 32M)

    convert_kernel<<<8192, 256, 0, stream>>>(x, xb);
    transpose_kernel<<<dim3(32, 32, 4), 256, 0, stream>>>(Wq, Wk, Wv, Wo, WT, WoT);
    gemm_kernel<0><<<dim3(24, 64), 256, 0, stream>>>(
        xb, WT, bq, bk, bv, nullptr, Qb, Kb, Vtb, nullptr, 3072, 1024);
    flash_kernel<<<dim3(64, 16), 256, 0, stream>>>(Qb, Kb, Vtb, Ob);
    gemm_kernel<1><<<dim3(8, 64), 256, 0, stream>>>(
        Ob, WoT, bo, nullptr, nullptr, x, nullptr, nullptr, nullptr, Tmpb, 1024, 1024);
    ln_kernel<<<8192, 256, 0, stream>>>(Tmpb, gamma, beta, out);
}